// Round 3
// baseline (3004.163 us; speedup 1.0000x reference)
//
#include <hip/hip_runtime.h>
#include <hip/hip_bf16.h>
#include <math.h>

#define S_LEN 2048
#define HID   1024
#define NHEAD 8
#define KVHEAD 4
#define HDIM  128
#define NEXP  8
#define FFDIM 2048
#define SCALING 0.08838834764831845f   /* 128^-0.5 */
#define SOFTCAP 50.0f
#define RMS_EPS 1e-6f
#define JITTER2 0.02f                  /* 2*jitter */
#define NEGBIG  -1e30f

#define GT 64
#define GK 16
#define GPAD 68   /* rows stay 16B-aligned (68*4=272B), +4 bank shift */

// ---------------------------------------------------------------- RMS norm
// out[row] = (HAS_RES ? res[row] : 0) + normalize(in1[row] (+ in2[row])) * (1+w)
template<bool HAS_RES, bool HAS_IN2>
__global__ __launch_bounds__(256)
void rms_kernel(const float* __restrict__ in1, const float* __restrict__ in2,
                const float* __restrict__ res, const float* __restrict__ w,
                float* __restrict__ out) {
    int row = blockIdx.x;
    int tid = threadIdx.x;                 // 256 threads * float4 = 1024
    float4 a = ((const float4*)(in1 + (size_t)row * HID))[tid];
    if (HAS_IN2) {
        float4 b = ((const float4*)(in2 + (size_t)row * HID))[tid];
        a.x += b.x; a.y += b.y; a.z += b.z; a.w += b.w;
    }
    float ss = a.x*a.x + a.y*a.y + a.z*a.z + a.w*a.w;
    #pragma unroll
    for (int off = 1; off < 64; off <<= 1) ss += __shfl_xor(ss, off);
    __shared__ float wsum[4];
    if ((tid & 63) == 0) wsum[tid >> 6] = ss;
    __syncthreads();
    float tot = wsum[0] + wsum[1] + wsum[2] + wsum[3];
    float inv = 1.0f / sqrtf(tot / (float)HID + RMS_EPS);
    float4 wv = ((const float4*)w)[tid];
    float4 o;
    o.x = a.x * inv * (1.0f + wv.x);
    o.y = a.y * inv * (1.0f + wv.y);
    o.z = a.z * inv * (1.0f + wv.z);
    o.w = a.w * inv * (1.0f + wv.w);
    if (HAS_RES) {
        float4 r = ((const float4*)(res + (size_t)row * HID))[tid];
        o.x += r.x; o.y += r.y; o.z += r.z; o.w += r.w;
    }
    ((float4*)(out + (size_t)row * HID))[tid] = o;
}

// ---------------------------------------------------------------- GEMM C = A(MxK) * B(NxK)^T
__global__ __launch_bounds__(256)
void gemm_nt(const float* __restrict__ A, const float* __restrict__ B,
             float* __restrict__ C, int M, int N, int K) {
    __shared__ float As[GK][GPAD];
    __shared__ float Bs[GK][GPAD];
    int tid = threadIdx.x;
    int ty = tid >> 4, tx = tid & 15;
    int m0 = blockIdx.x * GT, n0 = blockIdx.y * GT;
    int lrow = tid >> 2;            // 0..63
    int lk4  = (tid & 3) << 2;      // 0,4,8,12
    const float* Ap = A + (size_t)(m0 + lrow) * K + lk4;
    const float* Bp = B + (size_t)(n0 + lrow) * K + lk4;
    float c[4][4] = {};
    for (int k0 = 0; k0 < K; k0 += GK) {
        float4 av = *(const float4*)(Ap + k0);
        float4 bv = *(const float4*)(Bp + k0);
        As[lk4+0][lrow]=av.x; As[lk4+1][lrow]=av.y; As[lk4+2][lrow]=av.z; As[lk4+3][lrow]=av.w;
        Bs[lk4+0][lrow]=bv.x; Bs[lk4+1][lrow]=bv.y; Bs[lk4+2][lrow]=bv.z; Bs[lk4+3][lrow]=bv.w;
        __syncthreads();
        #pragma unroll
        for (int kk = 0; kk < GK; kk++) {
            float4 a4 = *(const float4*)&As[kk][ty*4];   // ds_read_b128
            float4 b4 = *(const float4*)&Bs[kk][tx*4];   // ds_read_b128
            float a[4] = {a4.x, a4.y, a4.z, a4.w};
            float b[4] = {b4.x, b4.y, b4.z, b4.w};
            #pragma unroll
            for (int i = 0; i < 4; i++)
                #pragma unroll
                for (int j = 0; j < 4; j++) c[i][j] += a[i]*b[j];
        }
        __syncthreads();
    }
    #pragma unroll
    for (int i = 0; i < 4; i++) {
        int m = m0 + ty*4 + i;
        float4 v = make_float4(c[i][0], c[i][1], c[i][2], c[i][3]);
        *(float4*)(C + (size_t)m * N + n0 + tx*4) = v;
    }
}

// ---------------------------------------------------------------- RoPE (in-place on q,k)
__global__ __launch_bounds__(256)
void rope_kernel(float* __restrict__ q, float* __restrict__ k,
                 const float* __restrict__ cosb, const float* __restrict__ sinb) {
    int t = blockIdx.x;
    const float* cr = cosb + (size_t)t * HDIM;
    const float* sr = sinb + (size_t)t * HDIM;
    for (int id = threadIdx.x; id < 768; id += 256) {
        float* base; int hh, d;
        if (id < 512) { base = q + (size_t)t * 1024; hh = id >> 6; d = id & 63; }
        else          { base = k + (size_t)t * 512;  hh = (id - 512) >> 6; d = id & 63; }
        float x0 = base[hh*HDIM + d], x1 = base[hh*HDIM + d + 64];
        float c0 = cr[d], c1 = cr[d + 64], s0 = sr[d], s1 = sr[d + 64];
        base[hh*HDIM + d]      = x0 * c0 - x1 * s0;
        base[hh*HDIM + d + 64] = x1 * c1 + x0 * s1;
    }
}

// ---------------------------------------------------------------- Flash attention (fp32, causal, softcap)
__global__ __launch_bounds__(256)
void flash_attn(const float* __restrict__ q, const float* __restrict__ k,
                const float* __restrict__ v, float* __restrict__ o) {
    int h = blockIdx.y;
    int kvh = h >> 1;
    int q0 = blockIdx.x * 64;
    __shared__ float Qs[64][HDIM + 4];   // rows 16B-aligned, +4 bank shift
    __shared__ float Ks[64][HDIM + 4];
    __shared__ float Vs[64][HDIM + 4];
    __shared__ float Ps[64][GPAD];
    int tid = threadIdx.x, ty = tid >> 4, tx = tid & 15;
    for (int i = tid; i < 64 * 32; i += 256) {
        int r = i >> 5, c4 = (i & 31) << 2;
        float4 val = *(const float4*)(q + (size_t)(q0 + r) * 1024 + h * HDIM + c4);
        *(float4*)&Qs[r][c4] = val;
    }
    float acc[4][8] = {};
    float mrun[4], lrun[4];
    #pragma unroll
    for (int i = 0; i < 4; i++) { mrun[i] = NEGBIG; lrun[i] = 0.0f; }

    for (int k0 = 0; k0 <= q0; k0 += 64) {
        __syncthreads();
        for (int i = tid; i < 64 * 32; i += 256) {
            int r = i >> 5, c4 = (i & 31) << 2;
            float4 kv = *(const float4*)(k + (size_t)(k0 + r) * 512 + kvh * HDIM + c4);
            *(float4*)&Ks[r][c4] = kv;
            float4 vv = *(const float4*)(v + (size_t)(k0 + r) * 512 + kvh * HDIM + c4);
            *(float4*)&Vs[r][c4] = vv;
        }
        __syncthreads();
        float s[4][4] = {};
        #pragma unroll 4
        for (int kk = 0; kk < HDIM; kk++) {
            float a[4], b[4];
            #pragma unroll
            for (int i = 0; i < 4; i++) a[i] = Qs[ty*4+i][kk];
            #pragma unroll
            for (int j = 0; j < 4; j++) b[j] = Ks[tx*4+j][kk];
            #pragma unroll
            for (int i = 0; i < 4; i++)
                #pragma unroll
                for (int j = 0; j < 4; j++) s[i][j] += a[i]*b[j];
        }
        #pragma unroll
        for (int i = 0; i < 4; i++) {
            int qr = q0 + ty*4 + i;
            float sv[4];
            float mx = NEGBIG;
            #pragma unroll
            for (int j = 0; j < 4; j++) {
                int kc = k0 + tx*4 + j;
                float val = tanhf(s[i][j] * (SCALING / SOFTCAP)) * SOFTCAP;
                if (kc > qr) val = NEGBIG;
                sv[j] = val;
                mx = fmaxf(mx, val);
            }
            #pragma unroll
            for (int off = 1; off < 16; off <<= 1) mx = fmaxf(mx, __shfl_xor(mx, off));
            float mn = fmaxf(mrun[i], mx);
            float p4[4], sum = 0.0f;
            #pragma unroll
            for (int j = 0; j < 4; j++) { p4[j] = expf(sv[j] - mn); sum += p4[j]; }
            #pragma unroll
            for (int off = 1; off < 16; off <<= 1) sum += __shfl_xor(sum, off);
            float scale = expf(mrun[i] - mn);
            lrun[i] = lrun[i] * scale + sum;
            mrun[i] = mn;
            #pragma unroll
            for (int jd = 0; jd < 8; jd++) acc[i][jd] *= scale;
            #pragma unroll
            for (int j = 0; j < 4; j++) Ps[ty*4+i][tx*4+j] = p4[j];
        }
        __syncthreads();
        #pragma unroll 4
        for (int kk = 0; kk < 64; kk++) {
            float p[4];
            #pragma unroll
            for (int i = 0; i < 4; i++) p[i] = Ps[ty*4+i][kk];
            float4 b0 = *(const float4*)&Vs[kk][tx*8];      // ds_read_b128
            float4 b1 = *(const float4*)&Vs[kk][tx*8+4];    // ds_read_b128
            float b[8] = {b0.x,b0.y,b0.z,b0.w,b1.x,b1.y,b1.z,b1.w};
            #pragma unroll
            for (int i = 0; i < 4; i++)
                #pragma unroll
                for (int jd = 0; jd < 8; jd++) acc[i][jd] += p[i]*b[jd];
        }
    }
    #pragma unroll
    for (int i = 0; i < 4; i++) {
        float invl = 1.0f / lrun[i];
        int qr = q0 + ty*4 + i;
        float4 v0 = make_float4(acc[i][0]*invl, acc[i][1]*invl, acc[i][2]*invl, acc[i][3]*invl);
        float4 v1 = make_float4(acc[i][4]*invl, acc[i][5]*invl, acc[i][6]*invl, acc[i][7]*invl);
        *(float4*)(o + (size_t)qr * 1024 + h*HDIM + tx*8)     = v0;
        *(float4*)(o + (size_t)qr * 1024 + h*HDIM + tx*8 + 4) = v1;
    }
}

// ---------------------------------------------------------------- Router + sparsemixer (eval)
__global__ __launch_bounds__(64)
void router_kernel(const float* __restrict__ xm, const float* __restrict__ wr,
                   int* __restrict__ sel, float* __restrict__ mult,
                   int* __restrict__ counts) {
    int t = blockIdx.x;
    int lane = threadIdx.x;
    const float* xr = xm + (size_t)t * HID;
    float xv[16];
    #pragma unroll
    for (int i = 0; i < 16; i++) xv[i] = xr[lane + 64*i];
    float sc[NEXP];
    for (int e = 0; e < NEXP; e++) {
        const float* wre = wr + e * HID;
        float sum = 0.0f;
        #pragma unroll
        for (int i = 0; i < 16; i++) sum += xv[i] * wre[lane + 64*i];
        #pragma unroll
        for (int off = 1; off < 64; off <<= 1) sum += __shfl_xor(sum, off);
        sc[e] = sum;
    }
    if (lane == 0) {
        // top-1
        float m1 = -INFINITY; int s1 = 0;
        for (int e = 0; e < NEXP; e++) if (sc[e] > m1) { m1 = sc[e]; s1 = e; }
        float g[NEXP], mx = -INFINITY;
        for (int e = 0; e < NEXP; e++) {
            float a = ((m1 - sc[e]) / fmaxf(fabsf(sc[e]), m1) > JITTER2) ? NEGBIG : sc[e];
            g[e] = a; mx = fmaxf(mx, a);
        }
        float den = 0.0f;
        for (int e = 0; e < NEXP; e++) { g[e] = expf(g[e] - mx); den += g[e]; }
        float mult1 = g[s1] / den;
        // top-2 on masked scores
        float ms[NEXP];
        for (int e = 0; e < NEXP; e++) ms[e] = (e == s1) ? NEGBIG : sc[e];
        float m2 = -INFINITY; int s2 = 0;
        for (int e = 0; e < NEXP; e++) if (ms[e] > m2) { m2 = ms[e]; s2 = e; }
        float g2[NEXP]; mx = -INFINITY;
        for (int e = 0; e < NEXP; e++) {
            float a = ((m2 - sc[e]) / fmaxf(fabsf(sc[e]), m2) > JITTER2) ? NEGBIG : ms[e];
            g2[e] = a; mx = fmaxf(mx, a);
        }
        den = 0.0f;
        for (int e = 0; e < NEXP; e++) { g2[e] = expf(g2[e] - mx); den += g2[e]; }
        float mult2 = g2[s2] / den;
        sel[t] = s1;  sel[S_LEN + t] = s2;
        mult[t] = mult1; mult[S_LEN + t] = mult2;
        atomicAdd(&counts[s1], 1);
        atomicAdd(&counts[s2], 1);
    }
}

__global__ void zero_small(int* counts, int* cursor) {
    if (threadIdx.x < NEXP) { counts[threadIdx.x] = 0; cursor[threadIdx.x] = 0; }
}
__global__ void scan_kernel(const int* counts, int* offsets) {
    if (threadIdx.x == 0) {
        int acc = 0;
        for (int e = 0; e < NEXP; e++) { offsets[e] = acc; acc += counts[e]; }
    }
}
__global__ __launch_bounds__(256)
void scatter_kernel(const int* __restrict__ sel, const float* __restrict__ mult,
                    const int* __restrict__ offsets, int* __restrict__ cursor,
                    int* __restrict__ list, float* __restrict__ wlist) {
    int t = blockIdx.x * 256 + threadIdx.x;
    if (t >= S_LEN) return;
    #pragma unroll
    for (int slot = 0; slot < 2; slot++) {
        int e = sel[slot * S_LEN + t];
        int pos = atomicAdd(&cursor[e], 1);
        int idx = offsets[e] + pos;
        list[idx] = t | (slot << 16);
        wlist[idx] = mult[slot * S_LEN + t];
    }
}

__device__ __forceinline__ float gelu_tanh(float x) {
    return 0.5f * x * (1.0f + tanhf(0.7978845608028654f * (x + 0.044715f * x * x * x)));
}

// ---------------------------------------------------------------- MoE stage A: act = gelu(X*w1^T) * (X*w3^T)
__global__ __launch_bounds__(256)
void moe_a_kernel(const float* __restrict__ xm, const float* __restrict__ w1,
                  const float* __restrict__ w3, const int* __restrict__ offsets,
                  const int* __restrict__ counts, const int* __restrict__ list,
                  float* __restrict__ act) {
    int e = blockIdx.z;
    int ne = counts[e];
    int m0 = blockIdx.x * GT;
    if (m0 >= ne) return;
    int base = offsets[e];
    int n0 = blockIdx.y * GT;
    const float* B1 = w1 + (size_t)e * FFDIM * HID;
    const float* B3 = w3 + (size_t)e * FFDIM * HID;
    __shared__ float As[GK][GPAD], B1s[GK][GPAD], B3s[GK][GPAD];
    int tid = threadIdx.x, ty = tid >> 4, tx = tid & 15;
    int lrow = tid >> 2, lk4 = (tid & 3) << 2;
    int gm = m0 + lrow;
    int tok = (gm < ne) ? (list[base + gm] & 0xffff) : -1;
    float c1[4][4] = {}, c3[4][4] = {};
    for (int k0 = 0; k0 < HID; k0 += GK) {
        float4 av = make_float4(0.f, 0.f, 0.f, 0.f);
        if (tok >= 0) av = *(const float4*)(xm + (size_t)tok * HID + lk4 + k0);
        float4 b1 = *(const float4*)(B1 + (size_t)(n0 + lrow) * HID + lk4 + k0);
        float4 b3 = *(const float4*)(B3 + (size_t)(n0 + lrow) * HID + lk4 + k0);
        As[lk4+0][lrow]=av.x; As[lk4+1][lrow]=av.y; As[lk4+2][lrow]=av.z; As[lk4+3][lrow]=av.w;
        B1s[lk4+0][lrow]=b1.x; B1s[lk4+1][lrow]=b1.y; B1s[lk4+2][lrow]=b1.z; B1s[lk4+3][lrow]=b1.w;
        B3s[lk4+0][lrow]=b3.x; B3s[lk4+1][lrow]=b3.y; B3s[lk4+2][lrow]=b3.z; B3s[lk4+3][lrow]=b3.w;
        __syncthreads();
        #pragma unroll
        for (int kk = 0; kk < GK; kk++) {
            float4 a4 = *(const float4*)&As[kk][ty*4];
            float4 b14 = *(const float4*)&B1s[kk][tx*4];
            float4 b34 = *(const float4*)&B3s[kk][tx*4];
            float a[4] = {a4.x, a4.y, a4.z, a4.w};
            float b1v[4] = {b14.x, b14.y, b14.z, b14.w};
            float b3v[4] = {b34.x, b34.y, b34.z, b34.w};
            #pragma unroll
            for (int i = 0; i < 4; i++)
                #pragma unroll
                for (int j = 0; j < 4; j++) { c1[i][j] += a[i]*b1v[j]; c3[i][j] += a[i]*b3v[j]; }
        }
        __syncthreads();
    }
    #pragma unroll
    for (int i = 0; i < 4; i++) {
        int m = m0 + ty*4 + i;
        if (m < ne) {
            float4 v;
            v.x = gelu_tanh(c1[i][0]) * c3[i][0];
            v.y = gelu_tanh(c1[i][1]) * c3[i][1];
            v.z = gelu_tanh(c1[i][2]) * c3[i][2];
            v.w = gelu_tanh(c1[i][3]) * c3[i][3];
            *(float4*)(act + (size_t)(base + m) * FFDIM + n0 + tx*4) = v;
        }
    }
}

// ---------------------------------------------------------------- MoE stage B: y = act * w2^T, scaled scatter
__global__ __launch_bounds__(256)
void moe_b_kernel(const float* __restrict__ act, const float* __restrict__ w2,
                  const int* __restrict__ offsets, const int* __restrict__ counts,
                  const int* __restrict__ list, const float* __restrict__ wlist,
                  float* __restrict__ buf0, float* __restrict__ buf1) {
    int e = blockIdx.z;
    int ne = counts[e];
    int m0 = blockIdx.x * GT;
    if (m0 >= ne) return;
    int base = offsets[e];
    int n0 = blockIdx.y * GT;
    const float* B = w2 + (size_t)e * HID * FFDIM;
    __shared__ float As[GK][GPAD], Bs[GK][GPAD];
    int tid = threadIdx.x, ty = tid >> 4, tx = tid & 15;
    int lrow = tid >> 2, lk4 = (tid & 3) << 2;
    int gm = m0 + lrow;
    bool arow = (gm < ne);
    float c[4][4] = {};
    for (int k0 = 0; k0 < FFDIM; k0 += GK) {
        float4 av = make_float4(0.f, 0.f, 0.f, 0.f);
        if (arow) av = *(const float4*)(act + (size_t)(base + gm) * FFDIM + lk4 + k0);
        float4 bv = *(const float4*)(B + (size_t)(n0 + lrow) * FFDIM + lk4 + k0);
        As[lk4+0][lrow]=av.x; As[lk4+1][lrow]=av.y; As[lk4+2][lrow]=av.z; As[lk4+3][lrow]=av.w;
        Bs[lk4+0][lrow]=bv.x; Bs[lk4+1][lrow]=bv.y; Bs[lk4+2][lrow]=bv.z; Bs[lk4+3][lrow]=bv.w;
        __syncthreads();
        #pragma unroll
        for (int kk = 0; kk < GK; kk++) {
            float4 a4 = *(const float4*)&As[kk][ty*4];
            float4 b4 = *(const float4*)&Bs[kk][tx*4];
            float a[4] = {a4.x, a4.y, a4.z, a4.w};
            float b[4] = {b4.x, b4.y, b4.z, b4.w};
            #pragma unroll
            for (int i = 0; i < 4; i++)
                #pragma unroll
                for (int j = 0; j < 4; j++) c[i][j] += a[i]*b[j];
        }
        __syncthreads();
    }
    #pragma unroll
    for (int i = 0; i < 4; i++) {
        int m = m0 + ty*4 + i;
        if (m < ne) {
            int entry = list[base + m];
            int t = entry & 0xffff;
            int slot = entry >> 16;
            float wgt = wlist[base + m];
            float* dst = (slot ? buf1 : buf0) + (size_t)t * HID + n0 + tx*4;
            float4 v = make_float4(c[i][0]*wgt, c[i][1]*wgt, c[i][2]*wgt, c[i][3]*wgt);
            *(float4*)dst = v;
        }
    }
}

// ---------------------------------------------------------------- launch
// Workspace budget (floats):
//   region A [0, 8M): x(2M) | qb(2M) | kb(1M) | vb(1M) | ob(2M)
//                     -- all dead after step 6; act(8M) aliases the whole region
//   hb   [ 8M,10M)
//   xmb  [10M,12M)
//   buf0 [12M,14M)
//   buf1 [14M,16M)
//   small tables at 16M (~17K elems)
// Total ~64 MB + 68 KB.
extern "C" void kernel_launch(void* const* d_in, const int* in_sizes, int n_in,
                              void* d_out, int out_size, void* d_ws, size_t ws_size,
                              hipStream_t stream) {
    const float* hidden = (const float*)d_in[0];
    const float* cosb   = (const float*)d_in[1];
    const float* sinb   = (const float*)d_in[2];
    /* d_in[3] attention_mask: implied by causal structure */
    const float* wq     = (const float*)d_in[4];
    const float* wk     = (const float*)d_in[5];
    const float* wv     = (const float*)d_in[6];
    const float* wo     = (const float*)d_in[7];
    const float* wr     = (const float*)d_in[8];
    const float* w1     = (const float*)d_in[9];
    const float* w2     = (const float*)d_in[10];
    const float* w3     = (const float*)d_in[11];
    const float* ln_in  = (const float*)d_in[12];
    const float* ln_pa  = (const float*)d_in[13];
    const float* ln_pf  = (const float*)d_in[14];
    const float* ln_po  = (const float*)d_in[15];
    float* out = (float*)d_out;

    const size_t SH = (size_t)S_LEN * HID;   // 2,097,152 floats
    float* ws   = (float*)d_ws;
    float* x    = ws;                        // 2M
    float* qb   = x + SH;                    // 2M
    float* kb   = qb + SH;                   // 1M
    float* vb   = kb + SH/2;                 // 1M
    float* ob   = vb + SH/2;                 // 2M
    float* act  = ws;                        // 8M, ALIASES x..ob (dead by then)
    float* hb   = ws + 4*SH;                 // 2M
    float* xmb  = hb + SH;                   // 2M
    float* buf0 = xmb + SH;                  // 2M
    float* buf1 = buf0 + SH;                 // 2M
    float* wlist = buf1 + SH;                // 4096
    float* multb = wlist + 2 * S_LEN;        // 4096
    int* sel     = (int*)(multb + 2 * S_LEN); // 4096
    int* counts  = sel + 2 * S_LEN;
    int* offsets = counts + NEXP;
    int* cursor  = offsets + NEXP;
    int* list    = cursor + NEXP;            // 4096

    // 1. input RMSNorm
    rms_kernel<false,false><<<S_LEN, 256, 0, stream>>>(hidden, nullptr, nullptr, ln_in, x);
    // 2. QKV projections
    gemm_nt<<<dim3(S_LEN/GT, 1024/GT), 256, 0, stream>>>(x, wq, qb, S_LEN, 1024, HID);
    gemm_nt<<<dim3(S_LEN/GT,  512/GT), 256, 0, stream>>>(x, wk, kb, S_LEN,  512, HID);
    gemm_nt<<<dim3(S_LEN/GT,  512/GT), 256, 0, stream>>>(x, wv, vb, S_LEN,  512, HID);
    // 3. RoPE
    rope_kernel<<<S_LEN, 256, 0, stream>>>(qb, kb, cosb, sinb);
    // 4. attention
    flash_attn<<<dim3(S_LEN/64, NHEAD), 256, 0, stream>>>(qb, kb, vb, ob);
    // 5. out-proj (into x, which is dead now)
    gemm_nt<<<dim3(S_LEN/GT, 1024/GT), 256, 0, stream>>>(ob, wo, x, S_LEN, 1024, HID);
    // 6. h = hidden + rms(attn_out)
    rms_kernel<true,false><<<S_LEN, 256, 0, stream>>>(x, nullptr, hidden, ln_pa, hb);
    // 7. xm = rms(h)
    rms_kernel<false,false><<<S_LEN, 256, 0, stream>>>(hb, nullptr, nullptr, ln_pf, xmb);
    // 8. routing
    zero_small<<<1, 64, 0, stream>>>(counts, cursor);
    router_kernel<<<S_LEN, 64, 0, stream>>>(xmb, wr, sel, multb, counts);
    scan_kernel<<<1, 64, 0, stream>>>(counts, offsets);
    scatter_kernel<<<(S_LEN + 255)/256, 256, 0, stream>>>(sel, multb, offsets, cursor, list, wlist);
    // 9. MoE (act aliases the attention-phase region, which is dead now)
    moe_a_kernel<<<dim3(S_LEN/GT, FFDIM/GT, NEXP), 256, 0, stream>>>(xmb, w1, w3, offsets, counts, list, act);
    moe_b_kernel<<<dim3(S_LEN/GT, HID/GT, NEXP), 256, 0, stream>>>(act, w2, offsets, counts, list, wlist, buf0, buf1);
    // 10. out = h + rms(buf0 + buf1)
    rms_kernel<true,true><<<S_LEN, 256, 0, stream>>>(buf0, buf1, hb, ln_po, out);
}

// Round 5
// 1667.726 us; speedup vs baseline: 1.8014x; 1.8014x over previous
//
#include <hip/hip_runtime.h>
#include <hip/hip_bf16.h>
#include <hip/hip_fp16.h>
#include <math.h>

#define S_LEN 2048
#define HID   1024
#define NHEAD 8
#define KVHEAD 4
#define HDIM  128
#define NEXP  8
#define FFDIM 2048
#define SCALING 0.08838834764831845f   /* 128^-0.5 */
#define SOFTCAP 50.0f
#define RMS_EPS 1e-6f
#define JITTER2 0.02f                  /* 2*jitter */
#define NEGBIG  -1e30f

#define GT 64
#define GK 16
#define GPAD 68   /* rows stay 16B-aligned (68*4=272B), +4 bank shift */

typedef _Float16 f16;
typedef __attribute__((ext_vector_type(8))) _Float16 half8;
typedef __attribute__((ext_vector_type(4))) float f32x4;

__device__ __forceinline__ unsigned short f2hu(float f) {
    f16 h = (f16)f;
    return *(unsigned short*)&h;
}

// ---------------------------------------------------------------- RMS norm
// out[row] = (HAS_RES ? res[row] : 0) + normalize(in1[row] (+ in2[row])) * (1+w)
template<bool HAS_RES, bool HAS_IN2, bool OUT16>
__global__ __launch_bounds__(256)
void rms_kernel(const float* __restrict__ in1, const float* __restrict__ in2,
                const float* __restrict__ res, const float* __restrict__ w,
                float* __restrict__ out, f16* __restrict__ out16) {
    int row = blockIdx.x;
    int tid = threadIdx.x;                 // 256 threads * float4 = 1024
    float4 a = ((const float4*)(in1 + (size_t)row * HID))[tid];
    if (HAS_IN2) {
        float4 b = ((const float4*)(in2 + (size_t)row * HID))[tid];
        a.x += b.x; a.y += b.y; a.z += b.z; a.w += b.w;
    }
    float ss = a.x*a.x + a.y*a.y + a.z*a.z + a.w*a.w;
    #pragma unroll
    for (int off = 1; off < 64; off <<= 1) ss += __shfl_xor(ss, off);
    __shared__ float wsum[4];
    if ((tid & 63) == 0) wsum[tid >> 6] = ss;
    __syncthreads();
    float tot = wsum[0] + wsum[1] + wsum[2] + wsum[3];
    float inv = 1.0f / sqrtf(tot / (float)HID + RMS_EPS);
    float4 wv = ((const float4*)w)[tid];
    float4 o;
    o.x = a.x * inv * (1.0f + wv.x);
    o.y = a.y * inv * (1.0f + wv.y);
    o.z = a.z * inv * (1.0f + wv.z);
    o.w = a.w * inv * (1.0f + wv.w);
    if (HAS_RES) {
        float4 r = ((const float4*)(res + (size_t)row * HID))[tid];
        o.x += r.x; o.y += r.y; o.z += r.z; o.w += r.w;
    }
    ((float4*)(out + (size_t)row * HID))[tid] = o;
    if (OUT16) {
        ushort4 u;
        u.x = f2hu(o.x); u.y = f2hu(o.y); u.z = f2hu(o.z); u.w = f2hu(o.w);
        ((ushort4*)(out16 + (size_t)row * HID))[tid] = u;
    }
}

// ---------------------------------------------------------------- GEMM C = A(MxK) * B(NxK)^T  (fp32, attention path)
__global__ __launch_bounds__(256)
void gemm_nt(const float* __restrict__ A, const float* __restrict__ B,
             float* __restrict__ C, int M, int N, int K) {
    __shared__ float As[GK][GPAD];
    __shared__ float Bs[GK][GPAD];
    int tid = threadIdx.x;
    int ty = tid >> 4, tx = tid & 15;
    int m0 = blockIdx.x * GT, n0 = blockIdx.y * GT;
    int lrow = tid >> 2;            // 0..63
    int lk4  = (tid & 3) << 2;      // 0,4,8,12
    const float* Ap = A + (size_t)(m0 + lrow) * K + lk4;
    const float* Bp = B + (size_t)(n0 + lrow) * K + lk4;
    float c[4][4] = {};
    for (int k0 = 0; k0 < K; k0 += GK) {
        float4 av = *(const float4*)(Ap + k0);
        float4 bv = *(const float4*)(Bp + k0);
        As[lk4+0][lrow]=av.x; As[lk4+1][lrow]=av.y; As[lk4+2][lrow]=av.z; As[lk4+3][lrow]=av.w;
        Bs[lk4+0][lrow]=bv.x; Bs[lk4+1][lrow]=bv.y; Bs[lk4+2][lrow]=bv.z; Bs[lk4+3][lrow]=bv.w;
        __syncthreads();
        #pragma unroll
        for (int kk = 0; kk < GK; kk++) {
            float4 a4 = *(const float4*)&As[kk][ty*4];   // ds_read_b128
            float4 b4 = *(const float4*)&Bs[kk][tx*4];   // ds_read_b128
            float a[4] = {a4.x, a4.y, a4.z, a4.w};
            float b[4] = {b4.x, b4.y, b4.z, b4.w};
            #pragma unroll
            for (int i = 0; i < 4; i++)
                #pragma unroll
                for (int j = 0; j < 4; j++) c[i][j] += a[i]*b[j];
        }
        __syncthreads();
    }
    #pragma unroll
    for (int i = 0; i < 4; i++) {
        int m = m0 + ty*4 + i;
        float4 v = make_float4(c[i][0], c[i][1], c[i][2], c[i][3]);
        *(float4*)(C + (size_t)m * N + n0 + tx*4) = v;
    }
}

// ---------------------------------------------------------------- RoPE (in-place on q,k)
__global__ __launch_bounds__(256)
void rope_kernel(float* __restrict__ q, float* __restrict__ k,
                 const float* __restrict__ cosb, const float* __restrict__ sinb) {
    int t = blockIdx.x;
    const float* cr = cosb + (size_t)t * HDIM;
    const float* sr = sinb + (size_t)t * HDIM;
    for (int id = threadIdx.x; id < 768; id += 256) {
        float* base; int hh, d;
        if (id < 512) { base = q + (size_t)t * 1024; hh = id >> 6; d = id & 63; }
        else          { base = k + (size_t)t * 512;  hh = (id - 512) >> 6; d = id & 63; }
        float x0 = base[hh*HDIM + d], x1 = base[hh*HDIM + d + 64];
        float c0 = cr[d], c1 = cr[d + 64], s0 = sr[d], s1 = sr[d + 64];
        base[hh*HDIM + d]      = x0 * c0 - x1 * s0;
        base[hh*HDIM + d + 64] = x1 * c1 + x0 * s1;
    }
}

// ---------------------------------------------------------------- Flash attention (fp32, causal, softcap)
__global__ __launch_bounds__(256)
void flash_attn(const float* __restrict__ q, const float* __restrict__ k,
                const float* __restrict__ v, float* __restrict__ o) {
    int h = blockIdx.y;
    int kvh = h >> 1;
    int q0 = blockIdx.x * 64;
    __shared__ float Qs[64][HDIM + 4];   // rows 16B-aligned, +4 bank shift
    __shared__ float Ks[64][HDIM + 4];
    __shared__ float Vs[64][HDIM + 4];
    __shared__ float Ps[64][GPAD];
    int tid = threadIdx.x, ty = tid >> 4, tx = tid & 15;
    for (int i = tid; i < 64 * 32; i += 256) {
        int r = i >> 5, c4 = (i & 31) << 2;
        float4 val = *(const float4*)(q + (size_t)(q0 + r) * 1024 + h * HDIM + c4);
        *(float4*)&Qs[r][c4] = val;
    }
    float acc[4][8] = {};
    float mrun[4], lrun[4];
    #pragma unroll
    for (int i = 0; i < 4; i++) { mrun[i] = NEGBIG; lrun[i] = 0.0f; }

    for (int k0 = 0; k0 <= q0; k0 += 64) {
        __syncthreads();
        for (int i = tid; i < 64 * 32; i += 256) {
            int r = i >> 5, c4 = (i & 31) << 2;
            float4 kv = *(const float4*)(k + (size_t)(k0 + r) * 512 + kvh * HDIM + c4);
            *(float4*)&Ks[r][c4] = kv;
            float4 vv = *(const float4*)(v + (size_t)(k0 + r) * 512 + kvh * HDIM + c4);
            *(float4*)&Vs[r][c4] = vv;
        }
        __syncthreads();
        float s[4][4] = {};
        #pragma unroll 4
        for (int kk = 0; kk < HDIM; kk++) {
            float a[4], b[4];
            #pragma unroll
            for (int i = 0; i < 4; i++) a[i] = Qs[ty*4+i][kk];
            #pragma unroll
            for (int j = 0; j < 4; j++) b[j] = Ks[tx*4+j][kk];
            #pragma unroll
            for (int i = 0; i < 4; i++)
                #pragma unroll
                for (int j = 0; j < 4; j++) s[i][j] += a[i]*b[j];
        }
        #pragma unroll
        for (int i = 0; i < 4; i++) {
            int qr = q0 + ty*4 + i;
            float sv[4];
            float mx = NEGBIG;
            #pragma unroll
            for (int j = 0; j < 4; j++) {
                int kc = k0 + tx*4 + j;
                float val = tanhf(s[i][j] * (SCALING / SOFTCAP)) * SOFTCAP;
                if (kc > qr) val = NEGBIG;
                sv[j] = val;
                mx = fmaxf(mx, val);
            }
            #pragma unroll
            for (int off = 1; off < 16; off <<= 1) mx = fmaxf(mx, __shfl_xor(mx, off));
            float mn = fmaxf(mrun[i], mx);
            float p4[4], sum = 0.0f;
            #pragma unroll
            for (int j = 0; j < 4; j++) { p4[j] = expf(sv[j] - mn); sum += p4[j]; }
            #pragma unroll
            for (int off = 1; off < 16; off <<= 1) sum += __shfl_xor(sum, off);
            float scale = expf(mrun[i] - mn);
            lrun[i] = lrun[i] * scale + sum;
            mrun[i] = mn;
            #pragma unroll
            for (int jd = 0; jd < 8; jd++) acc[i][jd] *= scale;
            #pragma unroll
            for (int j = 0; j < 4; j++) Ps[ty*4+i][tx*4+j] = p4[j];
        }
        __syncthreads();
        #pragma unroll 4
        for (int kk = 0; kk < 64; kk++) {
            float p[4];
            #pragma unroll
            for (int i = 0; i < 4; i++) p[i] = Ps[ty*4+i][kk];
            float4 b0 = *(const float4*)&Vs[kk][tx*8];      // ds_read_b128
            float4 b1 = *(const float4*)&Vs[kk][tx*8+4];    // ds_read_b128
            float b[8] = {b0.x,b0.y,b0.z,b0.w,b1.x,b1.y,b1.z,b1.w};
            #pragma unroll
            for (int i = 0; i < 4; i++)
                #pragma unroll
                for (int jd = 0; jd < 8; jd++) acc[i][jd] += p[i]*b[jd];
        }
    }
    #pragma unroll
    for (int i = 0; i < 4; i++) {
        float invl = 1.0f / lrun[i];
        int qr = q0 + ty*4 + i;
        float4 v0 = make_float4(acc[i][0]*invl, acc[i][1]*invl, acc[i][2]*invl, acc[i][3]*invl);
        float4 v1 = make_float4(acc[i][4]*invl, acc[i][5]*invl, acc[i][6]*invl, acc[i][7]*invl);
        *(float4*)(o + (size_t)qr * 1024 + h*HDIM + tx*8)     = v0;
        *(float4*)(o + (size_t)qr * 1024 + h*HDIM + tx*8 + 4) = v1;
    }
}

// ---------------------------------------------------------------- Router + sparsemixer (eval)  -- FULL FP32
__global__ __launch_bounds__(64)
void router_kernel(const float* __restrict__ xm, const float* __restrict__ wr,
                   int* __restrict__ sel, float* __restrict__ mult,
                   int* __restrict__ counts) {
    int t = blockIdx.x;
    int lane = threadIdx.x;
    const float* xr = xm + (size_t)t * HID;
    float xv[16];
    #pragma unroll
    for (int i = 0; i < 16; i++) xv[i] = xr[lane + 64*i];
    float sc[NEXP];
    for (int e = 0; e < NEXP; e++) {
        const float* wre = wr + e * HID;
        float sum = 0.0f;
        #pragma unroll
        for (int i = 0; i < 16; i++) sum += xv[i] * wre[lane + 64*i];
        #pragma unroll
        for (int off = 1; off < 64; off <<= 1) sum += __shfl_xor(sum, off);
        sc[e] = sum;
    }
    if (lane == 0) {
        // top-1
        float m1 = -INFINITY; int s1 = 0;
        for (int e = 0; e < NEXP; e++) if (sc[e] > m1) { m1 = sc[e]; s1 = e; }
        float g[NEXP], mx = -INFINITY;
        for (int e = 0; e < NEXP; e++) {
            float a = ((m1 - sc[e]) / fmaxf(fabsf(sc[e]), m1) > JITTER2) ? NEGBIG : sc[e];
            g[e] = a; mx = fmaxf(mx, a);
        }
        float den = 0.0f;
        for (int e = 0; e < NEXP; e++) { g[e] = expf(g[e] - mx); den += g[e]; }
        float mult1 = g[s1] / den;
        // top-2 on masked scores
        float ms[NEXP];
        for (int e = 0; e < NEXP; e++) ms[e] = (e == s1) ? NEGBIG : sc[e];
        float m2 = -INFINITY; int s2 = 0;
        for (int e = 0; e < NEXP; e++) if (ms[e] > m2) { m2 = ms[e]; s2 = e; }
        float g2[NEXP]; mx = -INFINITY;
        for (int e = 0; e < NEXP; e++) {
            float a = ((m2 - sc[e]) / fmaxf(fabsf(sc[e]), m2) > JITTER2) ? NEGBIG : ms[e];
            g2[e] = a; mx = fmaxf(mx, a);
        }
        den = 0.0f;
        for (int e = 0; e < NEXP; e++) { g2[e] = expf(g2[e] - mx); den += g2[e]; }
        float mult2 = g2[s2] / den;
        sel[t] = s1;  sel[S_LEN + t] = s2;
        mult[t] = mult1; mult[S_LEN + t] = mult2;
        atomicAdd(&counts[s1], 1);
        atomicAdd(&counts[s2], 1);
    }
}

__global__ void zero_small(int* counts, int* cursor) {
    if (threadIdx.x < NEXP) { counts[threadIdx.x] = 0; cursor[threadIdx.x] = 0; }
}
__global__ void scan_kernel(const int* counts, int* offsets) {
    if (threadIdx.x == 0) {
        int acc = 0;
        for (int e = 0; e < NEXP; e++) { offsets[e] = acc; acc += counts[e]; }
    }
}
__global__ __launch_bounds__(256)
void scatter_kernel(const int* __restrict__ sel, const float* __restrict__ mult,
                    const int* __restrict__ offsets, int* __restrict__ cursor,
                    int* __restrict__ list, float* __restrict__ wlist) {
    int t = blockIdx.x * 256 + threadIdx.x;
    if (t >= S_LEN) return;
    #pragma unroll
    for (int slot = 0; slot < 2; slot++) {
        int e = sel[slot * S_LEN + t];
        int pos = atomicAdd(&cursor[e], 1);
        int idx = offsets[e] + pos;
        list[idx] = t | (slot << 16);
        wlist[idx] = mult[slot * S_LEN + t];
    }
}

__device__ __forceinline__ float gelu_tanh(float x) {
    return 0.5f * x * (1.0f + tanhf(0.7978845608028654f * (x + 0.044715f * x * x * x)));
}

// ================================================================ MoE stage A (MFMA fp16)
// act[base+m][n] = f16( gelu(xm@w1e^T) * (xm@w3e^T) )
// Tile: BM=128, BN=64 (dual B), BK=64. 4 waves (2x2): wave tile 64x32 per output.
// LDS XOR swizzle: 16B slot s at row r stored at slot (s ^ (r&7)).
__global__ __launch_bounds__(256)
void moe_a_mfma(const f16* __restrict__ xm16,
                const float* __restrict__ w1, const float* __restrict__ w3,
                const int* __restrict__ offsets, const int* __restrict__ counts,
                const int* __restrict__ list,
                f16* __restrict__ act) {
    int e = blockIdx.z;
    int ne = counts[e];
    int m0 = blockIdx.x * 128;
    if (m0 >= ne) return;
    int base = offsets[e];
    int n0 = blockIdx.y * 64;
    const float* B1g = w1 + (size_t)e * FFDIM * HID + (size_t)n0 * HID;
    const float* B3g = w3 + (size_t)e * FFDIM * HID + (size_t)n0 * HID;

    __shared__ f16 Al[128 * 64];
    __shared__ f16 B1l[64 * 64];
    __shared__ f16 B3l[64 * 64];

    int tid = threadIdx.x;
    int lane = tid & 63, wid = tid >> 6;
    int wr = wid >> 1, wc = wid & 1;
    int lm = lane & 15, g = lane >> 4;

    // A staging: thread owns row (tid&127), slots {s0, s0+2, s0+4, s0+6}, s0 = tid>>7
    int arow = tid & 127;
    int as0 = tid >> 7;
    int gmr = m0 + arow;
    int tok = list[base + (gmr < ne ? gmr : 0)] & 0xffff;
    const f16* Ag = xm16 + (size_t)tok * HID;
    // B staging: thread owns row (tid&63), slots {bs0, bs0+4}, bs0 = tid>>6
    int brow = tid & 63;
    int bs0 = tid >> 6;
    const float* B1r = B1g + (size_t)brow * HID;
    const float* B3r = B3g + (size_t)brow * HID;

    f32x4 acc1[4][2], acc3[4][2];
    #pragma unroll
    for (int i = 0; i < 4; i++)
        #pragma unroll
        for (int j = 0; j < 2; j++)
            #pragma unroll
            for (int r = 0; r < 4; r++) { acc1[i][j][r] = 0.0f; acc3[i][j][r] = 0.0f; }

    for (int k0 = 0; k0 < HID; k0 += 64) {
        #pragma unroll
        for (int j = 0; j < 4; j++) {
            int s = as0 + 2*j;
            uint4 v = *(const uint4*)(Ag + k0 + s*8);
            *(uint4*)&Al[arow*64 + ((s ^ (arow & 7)) * 8)] = v;
        }
        #pragma unroll
        for (int j = 0; j < 2; j++) {
            int s = bs0 + 4*j;
            const float* p1 = B1r + k0 + s*8;
            float4 a = *(const float4*)p1, b = *(const float4*)(p1+4);
            half8 v1; v1[0]=(f16)a.x; v1[1]=(f16)a.y; v1[2]=(f16)a.z; v1[3]=(f16)a.w;
                      v1[4]=(f16)b.x; v1[5]=(f16)b.y; v1[6]=(f16)b.z; v1[7]=(f16)b.w;
            *(half8*)&B1l[brow*64 + ((s ^ (brow & 7)) * 8)] = v1;
            const float* p3 = B3r + k0 + s*8;
            float4 c = *(const float4*)p3, d = *(const float4*)(p3+4);
            half8 v3; v3[0]=(f16)c.x; v3[1]=(f16)c.y; v3[2]=(f16)c.z; v3[3]=(f16)c.w;
                      v3[4]=(f16)d.x; v3[5]=(f16)d.y; v3[6]=(f16)d.z; v3[7]=(f16)d.w;
            *(half8*)&B3l[brow*64 + ((s ^ (brow & 7)) * 8)] = v3;
        }
        __syncthreads();
        half8 af[4][2];
        #pragma unroll
        for (int mi = 0; mi < 4; mi++) {
            int row = wr*64 + mi*16 + lm;
            #pragma unroll
            for (int h = 0; h < 2; h++) {
                int slot = h*4 + g;
                af[mi][h] = *(const half8*)&Al[row*64 + ((slot ^ (row & 7)) * 8)];
            }
        }
        half8 b1f[2][2], b3f[2][2];
        #pragma unroll
        for (int ni = 0; ni < 2; ni++) {
            int row = wc*32 + ni*16 + lm;
            #pragma unroll
            for (int h = 0; h < 2; h++) {
                int off = row*64 + (((h*4 + g) ^ (row & 7)) * 8);
                b1f[ni][h] = *(const half8*)&B1l[off];
                b3f[ni][h] = *(const half8*)&B3l[off];
            }
        }
        #pragma unroll
        for (int h = 0; h < 2; h++)
            #pragma unroll
            for (int mi = 0; mi < 4; mi++)
                #pragma unroll
                for (int ni = 0; ni < 2; ni++) {
                    acc1[mi][ni] = __builtin_amdgcn_mfma_f32_16x16x32_f16(af[mi][h], b1f[ni][h], acc1[mi][ni], 0, 0, 0);
                    acc3[mi][ni] = __builtin_amdgcn_mfma_f32_16x16x32_f16(af[mi][h], b3f[ni][h], acc3[mi][ni], 0, 0, 0);
                }
        __syncthreads();
    }
    // epilogue: D[m][n], m = wr*64+mi*16+g*4+r, n = wc*32+ni*16+lm
    #pragma unroll
    for (int mi = 0; mi < 4; mi++) {
        #pragma unroll
        for (int r = 0; r < 4; r++) {
            int m = wr*64 + mi*16 + g*4 + r;
            if (m0 + m < ne) {
                size_t rowb = (size_t)(base + m0 + m) * FFDIM;
                #pragma unroll
                for (int ni = 0; ni < 2; ni++) {
                    int col = n0 + wc*32 + ni*16 + lm;
                    act[rowb + col] = (f16)(gelu_tanh(acc1[mi][ni][r]) * acc3[mi][ni][r]);
                }
            }
        }
    }
}

// ================================================================ MoE stage B (MFMA fp16)
// y = act @ w2e^T; scatter y*wgt into buf0/buf1 rows.
// Tile: BM=128, BN=128, BK=64. 4 waves (2x2): wave tile 64x64.
__global__ __launch_bounds__(256)
void moe_b_mfma(const f16* __restrict__ act, const float* __restrict__ w2,
                const int* __restrict__ offsets, const int* __restrict__ counts,
                const int* __restrict__ list, const float* __restrict__ wlist,
                float* __restrict__ buf0, float* __restrict__ buf1) {
    int e = blockIdx.z;
    int ne = counts[e];
    int m0 = blockIdx.x * 128;
    if (m0 >= ne) return;
    int base = offsets[e];
    int n0 = blockIdx.y * 128;
    const float* Bg = w2 + (size_t)e * HID * FFDIM + (size_t)n0 * FFDIM;

    __shared__ f16 Al[128 * 64];
    __shared__ f16 Bl[128 * 64];

    int tid = threadIdx.x;
    int lane = tid & 63, wid = tid >> 6;
    int wr = wid >> 1, wc = wid & 1;
    int lm = lane & 15, g = lane >> 4;

    // both A and B tiles: thread owns row (tid&127), slots {s0, s0+2, s0+4, s0+6}
    int arow = tid & 127;
    int s0 = tid >> 7;
    int gmr = m0 + arow;
    int ar = base + (gmr < ne ? gmr : (ne - 1));
    const f16* Ag = act + (size_t)ar * FFDIM;
    const float* Br = Bg + (size_t)arow * FFDIM;

    f32x4 acc[4][4];
    #pragma unroll
    for (int i = 0; i < 4; i++)
        #pragma unroll
        for (int j = 0; j < 4; j++)
            #pragma unroll
            for (int r = 0; r < 4; r++) acc[i][j][r] = 0.0f;

    for (int k0 = 0; k0 < FFDIM; k0 += 64) {
        #pragma unroll
        for (int j = 0; j < 4; j++) {
            int s = s0 + 2*j;
            uint4 v = *(const uint4*)(Ag + k0 + s*8);
            *(uint4*)&Al[arow*64 + ((s ^ (arow & 7)) * 8)] = v;
            const float* p = Br + k0 + s*8;
            float4 a = *(const float4*)p, b = *(const float4*)(p+4);
            half8 vb; vb[0]=(f16)a.x; vb[1]=(f16)a.y; vb[2]=(f16)a.z; vb[3]=(f16)a.w;
                      vb[4]=(f16)b.x; vb[5]=(f16)b.y; vb[6]=(f16)b.z; vb[7]=(f16)b.w;
            *(half8*)&Bl[arow*64 + ((s ^ (arow & 7)) * 8)] = vb;
        }
        __syncthreads();
        half8 af[4][2], bf[4][2];
        #pragma unroll
        for (int mi = 0; mi < 4; mi++) {
            int row = wr*64 + mi*16 + lm;
            #pragma unroll
            for (int h = 0; h < 2; h++)
                af[mi][h] = *(const half8*)&Al[row*64 + (((h*4 + g) ^ (row & 7)) * 8)];
        }
        #pragma unroll
        for (int ni = 0; ni < 4; ni++) {
            int row = wc*64 + ni*16 + lm;
            #pragma unroll
            for (int h = 0; h < 2; h++)
                bf[ni][h] = *(const half8*)&Bl[row*64 + (((h*4 + g) ^ (row & 7)) * 8)];
        }
        #pragma unroll
        for (int h = 0; h < 2; h++)
            #pragma unroll
            for (int mi = 0; mi < 4; mi++)
                #pragma unroll
                for (int ni = 0; ni < 4; ni++)
                    acc[mi][ni] = __builtin_amdgcn_mfma_f32_16x16x32_f16(af[mi][h], bf[ni][h], acc[mi][ni], 0, 0, 0);
        __syncthreads();
    }
    #pragma unroll
    for (int mi = 0; mi < 4; mi++) {
        #pragma unroll
        for (int r = 0; r < 4; r++) {
            int m = wr*64 + mi*16 + g*4 + r;
            if (m0 + m < ne) {
                int idx = base + m0 + m;
                int entry = list[idx];
                int t = entry & 0xffff;
                int slot = entry >> 16;
                float wgt = wlist[idx];
                float* dst = (slot ? buf1 : buf0) + (size_t)t * HID;
                #pragma unroll
                for (int ni = 0; ni < 4; ni++)
                    dst[n0 + wc*64 + ni*16 + lm] = acc[mi][ni][r] * wgt;
            }
        }
    }
}

// ---------------------------------------------------------------- launch
// Workspace (floats):
//  region A [0,8M): x[0,2M) qb[2M,4M) kb[4M,5M) vb[5M,6M) ob[6M,8M)   (attention temps)
//    act16 (f16, 4096x2048 = 4M float-equiv) aliases [0,4M)  -- written step 9, region dead
//    xm16  (f16, 2048x1024 = 1M float-equiv) aliases [4M,5M) -- written step 7, kb dead
//  hb[8M,10M) xmb[10M,12M) buf0[12M,14M) buf1[14M,16M)  tables at 16M.
// Total = 64 MB + ~68 KB (same footprint as the round-3 kernel that passed).
extern "C" void kernel_launch(void* const* d_in, const int* in_sizes, int n_in,
                              void* d_out, int out_size, void* d_ws, size_t ws_size,
                              hipStream_t stream) {
    const float* hidden = (const float*)d_in[0];
    const float* cosb   = (const float*)d_in[1];
    const float* sinb   = (const float*)d_in[2];
    /* d_in[3] attention_mask: implied by causal structure */
    const float* wq     = (const float*)d_in[4];
    const float* wk     = (const float*)d_in[5];
    const float* wv     = (const float*)d_in[6];
    const float* wo     = (const float*)d_in[7];
    const float* wr     = (const float*)d_in[8];
    const float* w1     = (const float*)d_in[9];
    const float* w2     = (const float*)d_in[10];
    const float* w3     = (const float*)d_in[11];
    const float* ln_in  = (const float*)d_in[12];
    const float* ln_pa  = (const float*)d_in[13];
    const float* ln_pf  = (const float*)d_in[14];
    const float* ln_po  = (const float*)d_in[15];
    float* out = (float*)d_out;

    const size_t SH = (size_t)S_LEN * HID;   // 2,097,152 floats
    float* ws   = (float*)d_ws;
    float* x    = ws;                        // [0,2M)
    float* qb   = x + SH;                    // [2M,4M)
    float* kb   = qb + SH;                   // [4M,5M)
    float* vb   = kb + SH/2;                 // [5M,6M)
    float* ob   = vb + SH/2;                 // [6M,8M)
    f16*   act16 = (f16*)ws;                 // [0,4M) floats = 16 MB, aliases x+qb
    f16*   xm16  = (f16*)(ws + 2*SH);        // [4M,5M) floats = 4 MB, aliases kb
    float* hb   = ws + 4*SH;                 // [8M,10M)
    float* xmb  = hb + SH;                   // [10M,12M)
    float* buf0 = xmb + SH;                  // [12M,14M)
    float* buf1 = buf0 + SH;                 // [14M,16M)
    float* wlist = buf1 + SH;                // 4096
    float* multb = wlist + 2 * S_LEN;        // 4096
    int* sel     = (int*)(multb + 2 * S_LEN); // 4096
    int* counts  = sel + 2 * S_LEN;
    int* offsets = counts + NEXP;
    int* cursor  = offsets + NEXP;
    int* list    = cursor + NEXP;            // 4096

    // 1. input RMSNorm
    rms_kernel<false,false,false><<<S_LEN, 256, 0, stream>>>(hidden, nullptr, nullptr, ln_in, x, nullptr);
    // 2. QKV projections (fp32 — feeds router-sensitive path)
    gemm_nt<<<dim3(S_LEN/GT, 1024/GT), 256, 0, stream>>>(x, wq, qb, S_LEN, 1024, HID);
    gemm_nt<<<dim3(S_LEN/GT,  512/GT), 256, 0, stream>>>(x, wk, kb, S_LEN,  512, HID);
    gemm_nt<<<dim3(S_LEN/GT,  512/GT), 256, 0, stream>>>(x, wv, vb, S_LEN,  512, HID);
    // 3. RoPE
    rope_kernel<<<S_LEN, 256, 0, stream>>>(qb, kb, cosb, sinb);
    // 4. attention
    flash_attn<<<dim3(S_LEN/64, NHEAD), 256, 0, stream>>>(qb, kb, vb, ob);
    // 5. out-proj (into x, which is dead now)
    gemm_nt<<<dim3(S_LEN/GT, 1024/GT), 256, 0, stream>>>(ob, wo, x, S_LEN, 1024, HID);
    // 6. h = hidden + rms(attn_out)
    rms_kernel<true,false,false><<<S_LEN, 256, 0, stream>>>(x, nullptr, hidden, ln_pa, hb, nullptr);
    // 7. xm = rms(h), fp32 for router + fp16 for MoE
    rms_kernel<false,false,true><<<S_LEN, 256, 0, stream>>>(hb, nullptr, nullptr, ln_pf, xmb, xm16);
    // 8. routing (fp32)
    zero_small<<<1, 64, 0, stream>>>(counts, cursor);
    router_kernel<<<S_LEN, 64, 0, stream>>>(xmb, wr, sel, multb, counts);
    scan_kernel<<<1, 64, 0, stream>>>(counts, offsets);
    scatter_kernel<<<(S_LEN + 255)/256, 256, 0, stream>>>(sel, multb, offsets, cursor, list, wlist);
    // 9. MoE (MFMA fp16; act16 aliases dead attention temps)
    moe_a_mfma<<<dim3(16, FFDIM/64, NEXP), 256, 0, stream>>>(xm16, w1, w3, offsets, counts, list, act16);
    moe_b_mfma<<<dim3(16, HID/128, NEXP), 256, 0, stream>>>(act16, w2, offsets, counts, list, wlist, buf0, buf1);
    // 10. out = h + rms(buf0 + buf1)
    rms_kernel<true,true,false><<<S_LEN, 256, 0, stream>>>(buf0, buf1, hb, ln_po, out, nullptr);
}